// Round 11
// baseline (1072.685 us; speedup 1.0000x reference)
//
#include <hip/hip_runtime.h>
#include <hip/hip_bf16.h>

typedef __attribute__((ext_vector_type(8)))  short short8;
typedef __attribute__((ext_vector_type(16))) float f32x16;

#define NVEC 65536   // B*H*W
#define KC   1024
#define DD   64

// d_out layout (f32): [0]=loss, [1..4194305)=z_q, [4194305]=ppl, [4194306..)=idx
#define OUT_ZQ   1
#define OUT_PPL  4194305
#define OUT_IDX  4194306

// out-region scratch (f32 offsets from out+OUT_ZQ): read ONLY by pre-zq kernels
#define SC_SZ    0         // f32[65536]
#define SC_SN    65536     // f32[65536]
#define SC_FBL   131072    // u32[65536]

// ws layout (bytes) -- max 663568, within proven ws capacity (R7 used 794632)
#define WS_FILT  0         // u32[65536] = 262144  (read by zq_kernel -> must be ws)
#define WS_HIST  262144    // int[1024]  = 4096
#define WS_SUMSQ 266240    // double     = 8
#define WS_FBCNT 266248    // u32        = 4 (+4 pad)
#define WS_SE    266256    // f32[1024]  = 4096
#define WS_EBF   270352    // bf16[1024][64] shuffled = 131072
#define WS_EMBT  401424    // f32[64][1024] = 262144

// ---------------------------------------------------------------------------
// prep_z: sz[n] = np.sum(zf**2) in numpy pairwise order (verified bit-exact),
// snv[n] = sum|z| for the rigorous error margin.
__global__ __launch_bounds__(256) void prep_z(const float* __restrict__ z,
                                              float* __restrict__ sz,
                                              float* __restrict__ snv) {
    const int n  = blockIdx.x * 256 + threadIdx.x;
    const int b  = n >> 10;
    const int hw = n & 1023;
    const float* zp = z + (size_t)b * 65536 + hw;
    float r[8];
    float sa = 0.0f;
    #pragma unroll
    for (int c = 0; c < 64; ++c) {
        float v = zp[(size_t)c * 1024];
        float s = __fmul_rn(v, v);
        if (c < 8) r[c] = s;
        else       r[c & 7] = __fadd_rn(r[c & 7], s);
        sa += fabsf(v);
    }
    sz[n] = __fadd_rn(__fadd_rn(__fadd_rn(r[0], r[1]), __fadd_rn(r[2], r[3])),
                      __fadd_rn(__fadd_rn(r[4], r[5]), __fadd_rn(r[6], r[7])));
    snv[n] = sa;
}

// prep_emb: se[k] (verified pairwise), shuffled bf16 rows for MFMA, and
// embT[c][k] f32 transpose for the exact fallback.
__global__ __launch_bounds__(256) void prep_emb(const float* __restrict__ emb,
                                                float* __restrict__ se,
                                                unsigned short* __restrict__ ebf,
                                                float* __restrict__ embT) {
    __shared__ float tile[64][65];
    const int tid = threadIdx.x;
    const int k0  = blockIdx.x * 64;
    {
        const int r = tid >> 2, q = tid & 3;
        const float* row = emb + (size_t)(k0 + r) * 64 + q * 16;
        #pragma unroll
        for (int i = 0; i < 4; ++i) {
            float4 v = *(const float4*)(row + i * 4);
            tile[r][q * 16 + i * 4 + 0] = v.x;
            tile[r][q * 16 + i * 4 + 1] = v.y;
            tile[r][q * 16 + i * 4 + 2] = v.z;
            tile[r][q * 16 + i * 4 + 3] = v.w;
        }
    }
    __syncthreads();
    if (tid < 64) {
        float r[8];
        #pragma unroll
        for (int c = 0; c < 64; ++c) {
            float v = tile[tid][c];
            float s = __fmul_rn(v, v);
            if (c < 8) r[c] = s;
            else       r[c & 7] = __fadd_rn(r[c & 7], s);
        }
        se[k0 + tid] = __fadd_rn(
            __fadd_rn(__fadd_rn(r[0], r[1]), __fadd_rn(r[2], r[3])),
            __fadd_rn(__fadd_rn(r[4], r[5]), __fadd_rn(r[6], r[7])));
    }
    const int kl = tid & 63, cg = tid >> 6;
    #pragma unroll
    for (int i = 0; i < 16; ++i) {
        int c = cg * 16 + i;
        embT[(size_t)c * KC + k0 + kl] = tile[kl][c];
    }
    unsigned* eb32 = (unsigned*)ebf;
    #pragma unroll
    for (int pp = 0; pp < 8; ++pp) {
        int p  = cg * 16 + pp * 2;
        int s  = p >> 4, rem = p & 15;
        int q  = rem >> 3, h = (rem >> 2) & 1, j = rem & 3;
        int c0 = s * 16 + 8 * h + 4 * q + j;
        __hip_bfloat16 b0 = __float2bfloat16(tile[kl][c0]);
        __hip_bfloat16 b1 = __float2bfloat16(tile[kl][c0 + 1]);
        unsigned u0 = *(unsigned short*)&b0;
        unsigned u1 = *(unsigned short*)&b1;
        eb32[((size_t)(k0 + kl) * 64 + p) >> 1] = u0 | (u1 << 16);
    }
}

// ---------------------------------------------------------------------------
// phase1: bf16 MFMA filter (layout HW-verified by R10's layout_test, lfail=0).
// Margin is the rigorous worst-case 2E even for RTZ cvt/accum:
//   E = Sn*(1/1024)*2*2^-7 * 2  =>  2E ~= Sn*6.14e-5  <  Sn*6.5e-5 + 4.5e-4.
// Unflagged => unique provable winner; flagged n -> exact fallback.
__global__ __launch_bounds__(256)
void phase1(const float* __restrict__ z,
            const unsigned short* __restrict__ ebf,
            const float* __restrict__ se,
            const float* __restrict__ sz,
            const float* __restrict__ snv,
            unsigned* __restrict__ filt,
            unsigned* __restrict__ fbcnt,
            unsigned* __restrict__ fblist) {
    __shared__ float    sK1d[4][64][16];
    __shared__ float    sK2d[4][64][16];
    __shared__ unsigned sK1k[4][64][16];

    const int tid = threadIdx.x;
    const int w   = tid >> 6;
    const int l   = tid & 63;
    const int q   = l >> 5;
    const int col = l & 31;
    const int nwave = blockIdx.x * 128 + w * 32;

    const int nA = nwave + col;
    const int bA = nA >> 10, hwA = nA & 1023;
    short8 af[4];
    #pragma unroll
    for (int s = 0; s < 4; ++s)
        #pragma unroll
        for (int h = 0; h < 2; ++h)
            #pragma unroll
            for (int j = 0; j < 4; ++j) {
                int c = s * 16 + 8 * h + 4 * q + j;
                float v = z[(size_t)bA * 65536 + (size_t)c * 1024 + hwA];
                __hip_bfloat16 bv = __float2bfloat16(v);
                af[s][4 * h + j] = *(short*)&bv;
            }

    float szr[16];
    #pragma unroll
    for (int g = 0; g < 4; ++g) {
        float4 t = *(const float4*)(sz + nwave + 4 * q + 8 * g);
        szr[4*g+0] = t.x; szr[4*g+1] = t.y; szr[4*g+2] = t.z; szr[4*g+3] = t.w;
    }

    float K1d[16], K2d[16]; unsigned K1k[16];
    #pragma unroll
    for (int r = 0; r < 16; ++r) { K1d[r] = K2d[r] = __builtin_inff(); K1k[r] = 0; }

    for (int t = 0; t < 32; ++t) {
        const int kcur = t * 32 + col;
        const unsigned short* eb = ebf + (size_t)kcur * 64 + q * 8;
        short8 b0 = *(const short8*)(eb + 0);
        short8 b1 = *(const short8*)(eb + 16);
        short8 b2 = *(const short8*)(eb + 32);
        short8 b3 = *(const short8*)(eb + 48);
        const float sek = se[kcur];
        f32x16 acc;
        #pragma unroll
        for (int r = 0; r < 16; ++r) acc[r] = 0.0f;
        acc = __builtin_amdgcn_mfma_f32_32x32x16_bf16(af[0], b0, acc, 0, 0, 0);
        acc = __builtin_amdgcn_mfma_f32_32x32x16_bf16(af[1], b1, acc, 0, 0, 0);
        acc = __builtin_amdgcn_mfma_f32_32x32x16_bf16(af[2], b2, acc, 0, 0, 0);
        acc = __builtin_amdgcn_mfma_f32_32x32x16_bf16(af[3], b3, acc, 0, 0, 0);
        #pragma unroll
        for (int r = 0; r < 16; ++r) {
            float d = __fmaf_rn(-2.0f, acc[r], __fadd_rn(szr[r], sek));
            bool c1 = d < K1d[r];
            bool c2 = d < K2d[r];
            K2d[r] = c1 ? K1d[r] : (c2 ? d : K2d[r]);
            K1k[r] = c1 ? (unsigned)kcur : K1k[r];
            K1d[r] = c1 ? d : K1d[r];
        }
    }

    #pragma unroll
    for (int r = 0; r < 16; ++r) {
        sK1d[w][l][r] = K1d[r];
        sK2d[w][l][r] = K2d[r];
        sK1k[w][l][r] = K1k[r];
    }
    __syncthreads();

    if (l < 32) {
        const int o = l;
        const int n = nwave + o;
        const int h = (o >> 2) & 1;
        const int s = (o & 3) + 4 * (o >> 3);
        float b1 = __builtin_inff(), b2 = __builtin_inff();
        unsigned bk = 0;
        for (int j = 0; j < 32; ++j) {
            float d = sK1d[w][h * 32 + j][s];
            unsigned kk = sK1k[w][h * 32 + j][s];
            bool better = (d < b1) || (d == b1 && kk < bk);
            if (better) { b2 = b1; b1 = d; bk = kk; }
            else        b2 = fminf(b2, d);
        }
        for (int j = 0; j < 32; ++j)
            b2 = fminf(b2, sK2d[w][h * 32 + j][s]);
        float margin = __fmaf_rn(snv[n], 6.5e-5f, 4.5e-4f);
        filt[n] = bk;
        if (b2 <= b1 + margin) {
            unsigned pos = atomicAdd(fbcnt, 1u);
            fblist[pos] = (unsigned)n;
        }
    }
}

// ---------------------------------------------------------------------------
// fallback: wave per flagged n; exact f32 scan of all 1024 codes with the
// verified sequential chain; first-index tie-break via (monotone<<10|k).
__global__ __launch_bounds__(256)
void fallback_kernel(const float* __restrict__ z,
                     const float* __restrict__ embT,
                     const float* __restrict__ se,
                     const float* __restrict__ sz,
                     const unsigned int* __restrict__ fbcnt,
                     const unsigned int* __restrict__ fblist,
                     unsigned* __restrict__ filt) {
    const int tid = threadIdx.x;
    const int w = tid >> 6, l = tid & 63;
    const unsigned total = *fbcnt;
    for (unsigned i = blockIdx.x * 4 + w; i < total; i += gridDim.x * 4) {
        const int n = (int)fblist[i];
        const int b = n >> 10, hw = n & 1023;
        float zl = z[(size_t)b * 65536 + (size_t)l * 1024 + hw];  // lane l = c
        float acc[16];
        #pragma unroll
        for (int p = 0; p < 16; ++p) acc[p] = 0.0f;
        for (int c = 0; c < 64; ++c) {
            float zc = __shfl(zl, c, 64);
            const float* eb = embT + (size_t)c * KC + l;
            #pragma unroll
            for (int p = 0; p < 16; ++p)
                acc[p] = __fmaf_rn(zc, eb[p * 64], acc[p]);
        }
        const float szn = sz[n];
        unsigned long long best = 0xFFFFFFFFFFFFFFFFULL;
        #pragma unroll
        for (int p = 0; p < 16; ++p) {
            int kp = l + p * 64;
            float d = __fmaf_rn(-2.0f, acc[p], __fadd_rn(szn, se[kp]));
            unsigned m = __float_as_uint(d);
            m ^= ((int)m < 0) ? 0xFFFFFFFFu : 0x80000000u;
            unsigned long long key =
                ((unsigned long long)m << 10) | (unsigned)kp;
            best = key < best ? key : best;
        }
        #pragma unroll
        for (int off = 32; off; off >>= 1) {
            unsigned long long o = __shfl_xor(best, off, 64);
            best = o < best ? o : best;
        }
        if (l == 0) filt[n] = (unsigned)(best & 1023ULL);
    }
}

// ---------------------------------------------------------------------------
// zq_kernel: idx out, hist, straight-through z_q, sumsq (idx from ws filt).
__global__ __launch_bounds__(256) void zq_kernel(const float* __restrict__ z,
                                                 const float* __restrict__ emb,
                                                 const unsigned* __restrict__ filt,
                                                 float* __restrict__ out,
                                                 int* __restrict__ hist,
                                                 double* __restrict__ sumsq) {
    __shared__ double red[256];
    const int tid = threadIdx.x;
    const int n   = blockIdx.x * 256 + tid;
    const int b   = n >> 10;
    const int hw  = n & 1023;
    const int idx = (int)(filt[n] & 1023u);

    out[OUT_IDX + n] = (float)idx;
    atomicAdd(&hist[idx], 1);

    const float* zp = z   + (size_t)b * 65536 + hw;
    float*       op = out + OUT_ZQ + (size_t)b * 65536 + hw;
    const float* er = emb + (size_t)idx * DD;
    double s = 0.0;
    #pragma unroll
    for (int c = 0; c < DD; ++c) {
        float zv   = zp[(size_t)c * 1024];
        float ev   = er[c];
        float diff = ev - zv;                  // z_q - z
        op[(size_t)c * 1024] = zv + diff;      // straight-through
        s = fma((double)diff, (double)diff, s);
    }
    red[tid] = s;
    __syncthreads();
    for (int off = 128; off > 0; off >>= 1) {
        if (tid < off) red[tid] += red[tid + off];
        __syncthreads();
    }
    if (tid == 0) atomicAdd(sumsq, red[0]);
}

__global__ __launch_bounds__(256) void final_kernel(const int* __restrict__ hist,
                                                    const double* __restrict__ sumsq,
                                                    float* __restrict__ out) {
    __shared__ double red[256];
    const int tid = threadIdx.x;
    double s = 0.0;
    #pragma unroll
    for (int j = 0; j < 4; ++j) {
        int   kk = j * 256 + tid;
        float em = (float)hist[kk] * (1.0f / 65536.0f);
        float t  = em * logf(em + 1e-10f);
        s += (double)t;
    }
    red[tid] = s;
    __syncthreads();
    for (int off = 128; off > 0; off >>= 1) {
        if (tid < off) red[tid] += red[tid + off];
        __syncthreads();
    }
    if (tid == 0) {
        out[OUT_PPL] = expf(-(float)red[0]);
        out[0]       = 1.25f * (float)(sumsq[0] / 4194304.0);
    }
}

extern "C" void kernel_launch(void* const* d_in, const int* in_sizes, int n_in,
                              void* d_out, int out_size, void* d_ws, size_t ws_size,
                              hipStream_t stream) {
    const float* z   = (const float*)d_in[0];
    const float* emb = (const float*)d_in[1];
    float* out = (float*)d_out;
    char*  ws  = (char*)d_ws;

    unsigned*       filt  = (unsigned*)(ws + WS_FILT);
    int*            hist  = (int*)(ws + WS_HIST);
    double*         sumsq = (double*)(ws + WS_SUMSQ);
    unsigned*       fbcnt = (unsigned*)(ws + WS_FBCNT);
    float*          se    = (float*)(ws + WS_SE);
    unsigned short* ebf   = (unsigned short*)(ws + WS_EBF);
    float*          embT  = (float*)(ws + WS_EMBT);

    float*    zscr   = out + OUT_ZQ;
    float*    sz     = zscr + SC_SZ;
    float*    snv    = zscr + SC_SN;
    unsigned* fblist = (unsigned*)(zscr + SC_FBL);

    hipMemsetAsync(ws + WS_HIST, 0, 4112, stream);  // hist + sumsq + fbcnt

    prep_z  <<<NVEC / 256, 256, 0, stream>>>(z, sz, snv);
    prep_emb<<<KC / 64,    256, 0, stream>>>(emb, se, ebf, embT);
    phase1  <<<NVEC / 128, 256, 0, stream>>>(z, ebf, se, sz, snv,
                                             filt, fbcnt, fblist);
    fallback_kernel<<<128, 256, 0, stream>>>(z, embT, se, sz, fbcnt, fblist, filt);
    zq_kernel      <<<NVEC / 256, 256, 0, stream>>>(z, emb, filt, out, hist, sumsq);
    final_kernel   <<<1, 256, 0, stream>>>(hist, sumsq, out);
}

// Round 12
// 161.564 us; speedup vs baseline: 6.6394x; 6.6394x over previous
//
#include <hip/hip_runtime.h>
#include <hip/hip_bf16.h>

typedef __attribute__((ext_vector_type(8)))  short short8;
typedef __attribute__((ext_vector_type(16))) float f32x16;

#define NVEC 65536   // B*H*W
#define KC   1024
#define DD   64

// d_out layout (f32): [0]=loss, [1..4194305)=z_q, [4194305]=ppl, [4194306..)=idx
#define OUT_ZQ   1
#define OUT_PPL  4194305
#define OUT_IDX  4194306

// out-region scratch (f32 offsets from out+OUT_ZQ): read only by pre-zq kernels
#define SC_SZ    0         // f32[65536]
#define SC_SN    65536     // f32[65536]
#define SC_FBL   131072    // u32[65536]

// ws layout (bytes) -- end 663568 < proven 794632 capacity
#define WS_FILT  0         // u16[65536] = 131072 (read by zq_kernel)
#define WS_HIST  131072    // int[1024]  = 4096
#define WS_SUMSQ 135168    // double     = 8
#define WS_FBCNT 135176    // u32 (+4 pad)
#define WS_SE    135184    // f32[1024]  = 4096
#define WS_EBFH  139280    // bf16[1024][64] shuffled (hi) = 131072
#define WS_EBFL  270352    // bf16[1024][64] shuffled (lo) = 131072
#define WS_EMBT  401424    // f32[64][1024] = 262144

// ---------------------------------------------------------------------------
// prep_z: sz[n] = np.sum(zf**2) in numpy pairwise order (verified bit-exact);
// snv[n] = sum|z| for the error margin.
__global__ __launch_bounds__(256) void prep_z(const float* __restrict__ z,
                                              float* __restrict__ sz,
                                              float* __restrict__ snv) {
    const int n  = blockIdx.x * 256 + threadIdx.x;
    const int b  = n >> 10;
    const int hw = n & 1023;
    const float* zp = z + (size_t)b * 65536 + hw;
    float r[8];
    float sa = 0.0f;
    #pragma unroll
    for (int c = 0; c < 64; ++c) {
        float v = zp[(size_t)c * 1024];
        float s = __fmul_rn(v, v);
        if (c < 8) r[c] = s;
        else       r[c & 7] = __fadd_rn(r[c & 7], s);
        sa += fabsf(v);
    }
    sz[n] = __fadd_rn(__fadd_rn(__fadd_rn(r[0], r[1]), __fadd_rn(r[2], r[3])),
                      __fadd_rn(__fadd_rn(r[4], r[5]), __fadd_rn(r[6], r[7])));
    snv[n] = sa;
}

// prep_emb: se[k] (verified pairwise), split-bf16 shuffled rows (hi+lo), and
// embT[c][k] f32 transpose for the exact fallback.
__global__ __launch_bounds__(256) void prep_emb(const float* __restrict__ emb,
                                                float* __restrict__ se,
                                                unsigned short* __restrict__ ebfh,
                                                unsigned short* __restrict__ ebfl,
                                                float* __restrict__ embT) {
    __shared__ float tile[64][65];
    const int tid = threadIdx.x;
    const int k0  = blockIdx.x * 64;
    {
        const int r = tid >> 2, q = tid & 3;
        const float* row = emb + (size_t)(k0 + r) * 64 + q * 16;
        #pragma unroll
        for (int i = 0; i < 4; ++i) {
            float4 v = *(const float4*)(row + i * 4);
            tile[r][q * 16 + i * 4 + 0] = v.x;
            tile[r][q * 16 + i * 4 + 1] = v.y;
            tile[r][q * 16 + i * 4 + 2] = v.z;
            tile[r][q * 16 + i * 4 + 3] = v.w;
        }
    }
    __syncthreads();
    if (tid < 64) {
        float r[8];
        #pragma unroll
        for (int c = 0; c < 64; ++c) {
            float v = tile[tid][c];
            float s = __fmul_rn(v, v);
            if (c < 8) r[c] = s;
            else       r[c & 7] = __fadd_rn(r[c & 7], s);
        }
        se[k0 + tid] = __fadd_rn(
            __fadd_rn(__fadd_rn(r[0], r[1]), __fadd_rn(r[2], r[3])),
            __fadd_rn(__fadd_rn(r[4], r[5]), __fadd_rn(r[6], r[7])));
    }
    const int kl = tid & 63, cg = tid >> 6;
    #pragma unroll
    for (int i = 0; i < 16; ++i) {
        int c = cg * 16 + i;
        embT[(size_t)c * KC + k0 + kl] = tile[kl][c];
    }
    unsigned* ebh32 = (unsigned*)ebfh;
    unsigned* ebl32 = (unsigned*)ebfl;
    #pragma unroll
    for (int pp = 0; pp < 8; ++pp) {
        int p  = cg * 16 + pp * 2;
        int s  = p >> 4, rem = p & 15;
        int q  = rem >> 3, h = (rem >> 2) & 1, j = rem & 3;
        int c0 = s * 16 + 8 * h + 4 * q + j;      // p, p+1 -> c0, c0+1
        float v0 = tile[kl][c0], v1 = tile[kl][c0 + 1];
        __hip_bfloat16 h0 = __float2bfloat16(v0);
        __hip_bfloat16 h1 = __float2bfloat16(v1);
        float r0 = v0 - __bfloat162float(h0);     // exact (Sterbenz)
        float r1 = v1 - __bfloat162float(h1);
        __hip_bfloat16 l0 = __float2bfloat16(r0);
        __hip_bfloat16 l1 = __float2bfloat16(r1);
        unsigned uh0 = *(unsigned short*)&h0, uh1 = *(unsigned short*)&h1;
        unsigned ul0 = *(unsigned short*)&l0, ul1 = *(unsigned short*)&l1;
        size_t widx = ((size_t)(k0 + kl) * 64 + p) >> 1;
        ebh32[widx] = uh0 | (uh1 << 16);
        ebl32[widx] = ul0 | (ul1 << 16);
    }
}

// ---------------------------------------------------------------------------
// phase1: split-bf16 MFMA filter. dot = zh*eh + zl*eh + zh*el (3 MFMAs/slab);
// residual vs exact f32 chain ~1e-6 -> margin snv*2e-7 + 6e-5 (2x cushion).
// Compares g_k = fl(se_k - 2 acc_k); sz is row-constant so argmin and gap
// transfer to d = fl(fl(sz+se)-2M) (shared-rounding analysis in notes).
// Unflagged => provable unique winner == numpy argmin; flagged -> fallback.
__global__ __launch_bounds__(256)
void phase1(const float* __restrict__ z,
            const unsigned short* __restrict__ ebfh,
            const unsigned short* __restrict__ ebfl,
            const float* __restrict__ se,
            const float* __restrict__ snv,
            unsigned short* __restrict__ filt,
            unsigned* __restrict__ fbcnt,
            unsigned* __restrict__ fblist) {
    __shared__ float    sK1d[4][64][16];
    __shared__ float    sK2d[4][64][16];
    __shared__ unsigned sK1k[4][64][16];

    const int tid = threadIdx.x;
    const int w   = tid >> 6;
    const int l   = tid & 63;
    const int q   = l >> 5;
    const int col = l & 31;
    const int nwave = blockIdx.x * 128 + w * 32;

    // A-frags: z split into hi+lo bf16. af*[s] elem (4h+j) <-> c = s*16+8h+4q+j
    const int nA = nwave + col;
    const int bA = nA >> 10, hwA = nA & 1023;
    short8 afh[4], afl[4];
    #pragma unroll
    for (int s = 0; s < 4; ++s)
        #pragma unroll
        for (int h = 0; h < 2; ++h)
            #pragma unroll
            for (int j = 0; j < 4; ++j) {
                int c = s * 16 + 8 * h + 4 * q + j;
                float v = z[(size_t)bA * 65536 + (size_t)c * 1024 + hwA];
                __hip_bfloat16 bh = __float2bfloat16(v);
                float rv = v - __bfloat162float(bh);
                __hip_bfloat16 bl = __float2bfloat16(rv);
                afh[s][4 * h + j] = *(short*)&bh;
                afl[s][4 * h + j] = *(short*)&bl;
            }

    float K1d[16], K2d[16]; unsigned K1k[16];
    #pragma unroll
    for (int r = 0; r < 16; ++r) { K1d[r] = K2d[r] = __builtin_inff(); K1k[r] = 0; }

    for (int t = 0; t < 32; ++t) {
        const int kcur = t * 32 + col;
        const unsigned short* ebh = ebfh + (size_t)kcur * 64 + q * 8;
        const unsigned short* ebl = ebfl + (size_t)kcur * 64 + q * 8;
        short8 bh0 = *(const short8*)(ebh + 0);
        short8 bh1 = *(const short8*)(ebh + 16);
        short8 bh2 = *(const short8*)(ebh + 32);
        short8 bh3 = *(const short8*)(ebh + 48);
        short8 bl0 = *(const short8*)(ebl + 0);
        short8 bl1 = *(const short8*)(ebl + 16);
        short8 bl2 = *(const short8*)(ebl + 32);
        short8 bl3 = *(const short8*)(ebl + 48);
        const float sek = se[kcur];
        f32x16 acc;
        #pragma unroll
        for (int r = 0; r < 16; ++r) acc[r] = 0.0f;
        acc = __builtin_amdgcn_mfma_f32_32x32x16_bf16(afh[0], bh0, acc, 0, 0, 0);
        acc = __builtin_amdgcn_mfma_f32_32x32x16_bf16(afl[0], bh0, acc, 0, 0, 0);
        acc = __builtin_amdgcn_mfma_f32_32x32x16_bf16(afh[0], bl0, acc, 0, 0, 0);
        acc = __builtin_amdgcn_mfma_f32_32x32x16_bf16(afh[1], bh1, acc, 0, 0, 0);
        acc = __builtin_amdgcn_mfma_f32_32x32x16_bf16(afl[1], bh1, acc, 0, 0, 0);
        acc = __builtin_amdgcn_mfma_f32_32x32x16_bf16(afh[1], bl1, acc, 0, 0, 0);
        acc = __builtin_amdgcn_mfma_f32_32x32x16_bf16(afh[2], bh2, acc, 0, 0, 0);
        acc = __builtin_amdgcn_mfma_f32_32x32x16_bf16(afl[2], bh2, acc, 0, 0, 0);
        acc = __builtin_amdgcn_mfma_f32_32x32x16_bf16(afh[2], bl2, acc, 0, 0, 0);
        acc = __builtin_amdgcn_mfma_f32_32x32x16_bf16(afh[3], bh3, acc, 0, 0, 0);
        acc = __builtin_amdgcn_mfma_f32_32x32x16_bf16(afl[3], bh3, acc, 0, 0, 0);
        acc = __builtin_amdgcn_mfma_f32_32x32x16_bf16(afh[3], bl3, acc, 0, 0, 0);
        #pragma unroll
        for (int r = 0; r < 16; ++r) {
            float d = __fmaf_rn(-2.0f, acc[r], sek);   // g_k (sz dropped: row-const)
            bool c1 = d < K1d[r];
            bool c2 = d < K2d[r];
            K2d[r] = c1 ? K1d[r] : (c2 ? d : K2d[r]);
            K1k[r] = c1 ? (unsigned)kcur : K1k[r];
            K1d[r] = c1 ? d : K1d[r];
        }
    }

    #pragma unroll
    for (int r = 0; r < 16; ++r) {
        sK1d[w][l][r] = K1d[r];
        sK2d[w][l][r] = K2d[r];
        sK1k[w][l][r] = K1k[r];
    }
    __syncthreads();

    if (l < 32) {
        const int o = l;
        const int n = nwave + o;
        const int h = (o >> 2) & 1;
        const int s = (o & 3) + 4 * (o >> 3);
        float b1 = __builtin_inff(), b2 = __builtin_inff();
        unsigned bk = 0;
        for (int j = 0; j < 32; ++j) {
            float d = sK1d[w][h * 32 + j][s];
            unsigned kk = sK1k[w][h * 32 + j][s];
            bool better = (d < b1) || (d == b1 && kk < bk);
            if (better) { b2 = b1; b1 = d; bk = kk; }
            else        b2 = fminf(b2, d);
        }
        for (int j = 0; j < 32; ++j)
            b2 = fminf(b2, sK2d[w][h * 32 + j][s]);
        float margin = __fmaf_rn(snv[n], 2.0e-7f, 6.0e-5f);
        filt[n] = (unsigned short)bk;
        if (b2 <= b1 + margin) {
            unsigned pos = atomicAdd(fbcnt, 1u);
            fblist[pos] = (unsigned)n;
        }
    }
}

// ---------------------------------------------------------------------------
// fallback: wave per flagged n; exact f32 scan of all 1024 codes with the
// verified sequential chain; first-index tie-break via (monotone<<10|k).
__global__ __launch_bounds__(256)
void fallback_kernel(const float* __restrict__ z,
                     const float* __restrict__ embT,
                     const float* __restrict__ se,
                     const float* __restrict__ sz,
                     const unsigned int* __restrict__ fbcnt,
                     const unsigned int* __restrict__ fblist,
                     unsigned short* __restrict__ filt) {
    const int tid = threadIdx.x;
    const int w = tid >> 6, l = tid & 63;
    const unsigned total = *fbcnt;
    for (unsigned i = blockIdx.x * 4 + w; i < total; i += gridDim.x * 4) {
        const int n = (int)fblist[i];
        const int b = n >> 10, hw = n & 1023;
        float zl = z[(size_t)b * 65536 + (size_t)l * 1024 + hw];  // lane l = c
        float acc[16];
        #pragma unroll
        for (int p = 0; p < 16; ++p) acc[p] = 0.0f;
        for (int c = 0; c < 64; ++c) {
            float zc = __shfl(zl, c, 64);
            const float* eb = embT + (size_t)c * KC + l;
            #pragma unroll
            for (int p = 0; p < 16; ++p)
                acc[p] = __fmaf_rn(zc, eb[p * 64], acc[p]);
        }
        const float szn = sz[n];
        unsigned long long best = 0xFFFFFFFFFFFFFFFFULL;
        #pragma unroll
        for (int p = 0; p < 16; ++p) {
            int kp = l + p * 64;
            float d = __fmaf_rn(-2.0f, acc[p], __fadd_rn(szn, se[kp]));
            unsigned m = __float_as_uint(d);
            m ^= ((int)m < 0) ? 0xFFFFFFFFu : 0x80000000u;
            unsigned long long key =
                ((unsigned long long)m << 10) | (unsigned)kp;
            best = key < best ? key : best;
        }
        #pragma unroll
        for (int off = 32; off; off >>= 1) {
            unsigned long long o = __shfl_xor(best, off, 64);
            best = o < best ? o : best;
        }
        if (l == 0) filt[n] = (unsigned short)(best & 1023ULL);
    }
}

// ---------------------------------------------------------------------------
// zq_kernel: idx out, hist, straight-through z_q, sumsq.
__global__ __launch_bounds__(256) void zq_kernel(const float* __restrict__ z,
                                                 const float* __restrict__ emb,
                                                 const unsigned short* __restrict__ filt,
                                                 float* __restrict__ out,
                                                 int* __restrict__ hist,
                                                 double* __restrict__ sumsq) {
    __shared__ double red[256];
    const int tid = threadIdx.x;
    const int n   = blockIdx.x * 256 + tid;
    const int b   = n >> 10;
    const int hw  = n & 1023;
    const int idx = (int)filt[n] & 1023;

    out[OUT_IDX + n] = (float)idx;
    atomicAdd(&hist[idx], 1);

    const float* zp = z   + (size_t)b * 65536 + hw;
    float*       op = out + OUT_ZQ + (size_t)b * 65536 + hw;
    const float* er = emb + (size_t)idx * DD;
    double s = 0.0;
    #pragma unroll
    for (int c = 0; c < DD; ++c) {
        float zv   = zp[(size_t)c * 1024];
        float ev   = er[c];
        float diff = ev - zv;                  // z_q - z
        op[(size_t)c * 1024] = zv + diff;      // straight-through
        s = fma((double)diff, (double)diff, s);
    }
    red[tid] = s;
    __syncthreads();
    for (int off = 128; off > 0; off >>= 1) {
        if (tid < off) red[tid] += red[tid + off];
        __syncthreads();
    }
    if (tid == 0) atomicAdd(sumsq, red[0]);
}

__global__ __launch_bounds__(256) void final_kernel(const int* __restrict__ hist,
                                                    const double* __restrict__ sumsq,
                                                    float* __restrict__ out) {
    __shared__ double red[256];
    const int tid = threadIdx.x;
    double s = 0.0;
    #pragma unroll
    for (int j = 0; j < 4; ++j) {
        int   kk = j * 256 + tid;
        float em = (float)hist[kk] * (1.0f / 65536.0f);
        float t  = em * logf(em + 1e-10f);
        s += (double)t;
    }
    red[tid] = s;
    __syncthreads();
    for (int off = 128; off > 0; off >>= 1) {
        if (tid < off) red[tid] += red[tid + off];
        __syncthreads();
    }
    if (tid == 0) {
        out[OUT_PPL] = expf(-(float)red[0]);
        out[0]       = 1.25f * (float)(sumsq[0] / 4194304.0);
    }
}

extern "C" void kernel_launch(void* const* d_in, const int* in_sizes, int n_in,
                              void* d_out, int out_size, void* d_ws, size_t ws_size,
                              hipStream_t stream) {
    const float* z   = (const float*)d_in[0];
    const float* emb = (const float*)d_in[1];
    float* out = (float*)d_out;
    char*  ws  = (char*)d_ws;

    unsigned short* filt  = (unsigned short*)(ws + WS_FILT);
    int*            hist  = (int*)(ws + WS_HIST);
    double*         sumsq = (double*)(ws + WS_SUMSQ);
    unsigned*       fbcnt = (unsigned*)(ws + WS_FBCNT);
    float*          se    = (float*)(ws + WS_SE);
    unsigned short* ebfh  = (unsigned short*)(ws + WS_EBFH);
    unsigned short* ebfl  = (unsigned short*)(ws + WS_EBFL);
    float*          embT  = (float*)(ws + WS_EMBT);

    float*    zscr   = out + OUT_ZQ;
    float*    sz     = zscr + SC_SZ;
    float*    snv    = zscr + SC_SN;
    unsigned* fblist = (unsigned*)(zscr + SC_FBL);

    hipMemsetAsync(ws + WS_HIST, 0, 4112, stream);  // hist + sumsq + fbcnt

    prep_z  <<<NVEC / 256, 256, 0, stream>>>(z, sz, snv);
    prep_emb<<<KC / 64,    256, 0, stream>>>(emb, se, ebfh, ebfl, embT);
    phase1  <<<NVEC / 128, 256, 0, stream>>>(z, ebfh, ebfl, se, snv,
                                             filt, fbcnt, fblist);
    fallback_kernel<<<128, 256, 0, stream>>>(z, embT, se, sz, fbcnt, fblist, filt);
    zq_kernel      <<<NVEC / 256, 256, 0, stream>>>(z, emb, filt, out, hist, sumsq);
    final_kernel   <<<1, 256, 0, stream>>>(hist, sumsq, out);
}